// Round 19
// baseline (103.336 us; speedup 1.0000x reference)
//
#include <hip/hip_runtime.h>
#include <hip/hip_bf16.h>
#include <stdint.h>
#include <math.h>

typedef __attribute__((ext_vector_type(8))) short bf8_t;    // 8 bf16 in 4 VGPRs
typedef __attribute__((ext_vector_type(4))) float f4_t;
typedef __attribute__((ext_vector_type(16))) float f16x_t;  // 32x32 mfma acc
typedef __attribute__((ext_vector_type(2))) unsigned u32x2;
typedef unsigned short u16;

#define GLOAD16(g, l) __builtin_amdgcn_global_load_lds(                                  \
    (const __attribute__((address_space(1))) void*)(g),                                  \
    (__attribute__((address_space(3))) void*)(l), 16, 0, 0)

#define KEEPALIVE(v) asm volatile("" : "+v"(v))

// Q pre-scale: (1/16) * log2(e)  -> softmax uses exp2 (bare v_exp_f32)
#define QSCALE 0.090168444f

__device__ __forceinline__ u16 f2bf(float f) {
    union { float f; unsigned u; } c; c.f = f;
    unsigned u = c.u;
    return (u16)((u + 0x7fffu + ((u >> 16) & 1u)) >> 16);   // RNE, inputs finite
}

__device__ __forceinline__ unsigned cvt_pk_bf16(float lo, float hi_) {
    unsigned r;
    asm("v_cvt_pk_bf16_f32 %0, %1, %2" : "=v"(r) : "v"(lo), "v"(hi_));
    return r;                                                // lo -> bits[15:0]
}

// v_permlane32_swap_b32: A[0:31] <-> B[32:63].
__device__ __forceinline__ void plswap(unsigned& a, unsigned& b) {
    u32x2 r = __builtin_amdgcn_permlane32_swap(a, b, false, false);
    a = r[0]; b = r[1];
}

// pack P fragments from 8 cvt_pk words: f0 = kv chunk0, f1 = kv chunk1
__device__ __forceinline__ void pack_frags(const unsigned* pw, bf8_t& f0v, bf8_t& f1v) {
    unsigned w0 = pw[0], w1 = pw[1], w2 = pw[2], w3 = pw[3];
    unsigned u0 = pw[4], u1 = pw[5], u2 = pw[6], u3 = pw[7];
    plswap(w2, w0);
    plswap(w3, w1);
    plswap(u2, u0);
    plswap(u3, u1);
    union { unsigned w[4]; bf8_t v; } f0, f1;
    f0.w[0] = w0; f0.w[1] = w1; f0.w[2] = w2; f0.w[3] = w3;
    f1.w[0] = u0; f1.w[1] = u1; f1.w[2] = u2; f1.w[3] = u3;
    f0v = f0.v; f1v = f1.v;
}

// ---------------- weights -> bf16 ----------------
// wcatT: [c>>3][768 out][8]  (QKV weights, chunked: fragment reads coalesce)
// wpt:   [d>>3][256 out][8]  (proj weights)
__global__ void prep_kernel(const float* __restrict__ wq, const float* __restrict__ wk,
                            const float* __restrict__ wv, const float* __restrict__ wp,
                            const float* __restrict__ bq, const float* __restrict__ bk,
                            const float* __restrict__ bv,
                            u16* __restrict__ wcatT, u16* __restrict__ wpt,
                            float* __restrict__ biasc) {
    int idx = blockIdx.x * 256 + threadIdx.x;
    if (idx < 196608) {                 // QKV weights
        int o = idx >> 8, c = idx & 255;
        float v = (o < 256) ? wq[o * 256 + c]
                : (o < 512) ? wk[(o - 256) * 256 + c]
                            : wv[(o - 512) * 256 + c];
        wcatT[(((c >> 3) * 768) + o) * 8 + (c & 7)] = f2bf(v);
    } else if (idx < 262144) {          // wp[o][d] -> wpt[(d>>3)][o][8]
        int i = idx - 196608;
        int o = i >> 8, d = i & 255;
        wpt[(((d >> 3) * 256) + o) * 8 + (d & 7)] = f2bf(wp[i]);
    } else if (idx < 262912) {          // bias concat [768]
        int i = idx - 262144;
        biasc[i] = (i < 256) ? bq[i] : (i < 512) ? bk[i - 256] : bv[i - 512];
    }
}

// ---------------- fused LayerNorm + QKV GEMM (v3: vectorized stores) ----------------
// grid 512 = (b, n-tile of 32); 256 threads = 4 waves; 18 KB LDS.
__global__ __launch_bounds__(256) void lnqkv_kernel(
    const float* __restrict__ x, const float* __restrict__ lw,
    const float* __restrict__ lb,
    const u16* __restrict__ wcatT, const float* __restrict__ biasc,
    u16* __restrict__ qbuf, u16* __restrict__ ktp, u16* __restrict__ vtp) {
    __shared__ u16 hn_lds[32 * 32 * 8];      // [chunk][tok][8], 16 KB
    __shared__ float2 red[8][32];            // 2 KB

    const int tid = threadIdx.x;
    const int bid = blockIdx.x;
    const int b = bid >> 5, n0 = (bid & 31) * 32;
    const int tok = tid & 31, cpart = tid >> 5;      // 8 parts x 32 channels

    // ---- LN: each thread owns 32 channels of one token ----
    const float* xb = x + (size_t)b * 262144 + n0 + tok;
    float v[32];
    float s = 0.f, s2 = 0.f;
    #pragma unroll
    for (int i = 0; i < 32; i++) {
        v[i] = xb[(size_t)(cpart * 32 + i) * 1024];
        s += v[i]; s2 += v[i] * v[i];
    }
    red[cpart][tok] = make_float2(s, s2);
    __syncthreads();
    s = 0.f; s2 = 0.f;
    #pragma unroll
    for (int gi = 0; gi < 8; gi++) { float2 p = red[gi][tok]; s += p.x; s2 += p.y; }
    float mean = s * 0.00390625f;
    float rstd = rsqrtf(s2 * 0.00390625f - mean * mean + 1e-6f);
    #pragma unroll
    for (int j = 0; j < 4; j++) {            // 4 chunks of 8 channels
        bf8_t pk;
        #pragma unroll
        for (int e = 0; e < 8; e++) {
            int c = cpart * 32 + j * 8 + e;
            pk[e] = (short)f2bf((v[j * 8 + e] - mean) * rstd * lw[c] + lb[c]);
        }
        *(bf8_t*)&hn_lds[((cpart * 4 + j) * 32 + tok) * 8] = pk;
    }
    __syncthreads();                         // hn complete; GEMM is barrier-free

    // ---- GEMM: out[32 tok][768], 24 col-tiles of 32, 6 per wave ----
    const int lane = tid & 63, wv_ = tid >> 6;
    const int hi = lane >> 5, lq = lane & 31;
    const int n = n0 + lq;

    // hn fragments: shared across all tiles of this wave
    bf8_t hnf[16];
    #pragma unroll
    for (int tc = 0; tc < 16; tc++)
        hnf[tc] = *(const bf8_t*)&hn_lds[((tc * 2 + hi) * 32 + lq) * 8];
    #pragma unroll
    for (int tc = 0; tc < 16; tc++) KEEPALIVE(hnf[tc]);

    #pragma unroll
    for (int grp = 0; grp < 3; grp++) {
        #pragma unroll
        for (int sub = 0; sub < 2; sub++) {
            const int cb = grp * 256 + (wv_ * 2 + sub) * 32;
            bf8_t wf[16];
            #pragma unroll
            for (int tc = 0; tc < 16; tc++)
                wf[tc] = *(const bf8_t*)(wcatT + (((size_t)(tc * 2 + hi) * 768) + cb + lq) * 8);
            f16x_t acc = (f16x_t)0.0f;
            if (grp < 2) {
                // swapped: lane = token, regs = channels
                #pragma unroll
                for (int tc = 0; tc < 16; tc++)
                    acc = __builtin_amdgcn_mfma_f32_32x32x16_bf16(wf[tc], hnf[tc], acc, 0, 0, 0);
                #pragma unroll
                for (int r = 0; r < 16; r++) {
                    float bv = biasc[cb + (r & 3) + 8 * (r >> 2) + 4 * hi];
                    acc[r] += bv;
                    if (grp == 0) acc[r] *= QSCALE;
                }
            } else {
                // normal: lane = channel d, regs = tokens
                #pragma unroll
                for (int tc = 0; tc < 16; tc++)
                    acc = __builtin_amdgcn_mfma_f32_32x32x16_bf16(hnf[tc], wf[tc], acc, 0, 0, 0);
                float bv = biasc[cb + lq];
                #pragma unroll
                for (int r = 0; r < 16; r++) acc[r] += bv;
            }

            unsigned pw[8];
            #pragma unroll
            for (int j = 0; j < 8; j++) pw[j] = cvt_pk_bf16(acc[2 * j], acc[2 * j + 1]);
            bf8_t f0v, f1v;
            pack_frags(pw, f0v, f1v);

            if (grp == 0) {                  // Q row-major [tok][256]
                u16* qb = &qbuf[((size_t)b * 1024 + n) * 256 + cb];
                *(bf8_t*)(qb + hi * 8) = f0v;
                *(bf8_t*)(qb + 16 + hi * 8) = f1v;
            } else if (grp == 1) {           // K -> kt[b][c>>3][n][8]
                int c0 = cb - 256 + hi * 8;
                *(bf8_t*)&ktp[(((size_t)b * 32 + (c0 >> 3)) * 1024 + n) * 8] = f0v;
                int c1 = c0 + 16;
                *(bf8_t*)&ktp[(((size_t)b * 32 + (c1 >> 3)) * 1024 + n) * 8] = f1v;
            } else {                         // V -> vt3[b][n>>3][d][8]
                int d = cb - 512 + lq;
                int t0 = n0 + hi * 8;
                *(bf8_t*)&vtp[(((size_t)b * 128 + (t0 >> 3)) * 256 + d) * 8] = f0v;
                int t1 = t0 + 16;
                *(bf8_t*)&vtp[(((size_t)b * 128 + (t1 >> 3)) * 256 + d) * 8] = f1v;
            }
        }
    }
}

// ---------------- flash attention + fused proj (V direct from L2) ----------------
// grid 512 = (b, qt 32-row tile) XCD-swizzled; 256 threads = 4 waves = (dw 2) x (g 2).
// K staged in LDS (dbuf, 64 KB total -> 2 blocks/CU); V fragments read straight
// from vt3 (coalesced 512B runs, L2-hot), no carried state. Single barrier/iter.
__global__ __launch_bounds__(256, 2)
void flash_kernel(const u16* __restrict__ qbuf,
                  const u16* __restrict__ kt,
                  const u16* __restrict__ vt3,
                  const u16* __restrict__ wpt,
                  const float* __restrict__ bp,
                  const float* __restrict__ x,
                  float* __restrict__ out) {
    __shared__ u16 K_lds[2][2][32 * 32 * 8];   // [g][buf][chunk][kv] 16B units, 64 KB
    __shared__ float lstat[32];

    const int flat = blockIdx.x;
    const int xcd = flat & 7, idx = flat >> 3;
    const int b = (xcd << 1) | (idx & 1);     // 2 batches per XCD -> KV fits L2
    const int qt = idx >> 1;                  // 0..31
    const int tid = threadIdx.x;
    const int wv = tid >> 6, lane = tid & 63;
    const int hi = lane >> 5, lq = lane & 31;
    const int dw = wv & 1, g = wv >> 1;

    // Q B-fragments: col=q=lq, chunk tc covers c = tc*16 + hi*8 + e
    const int qrow = qt * 32 + lq;
    const u16* qptr = qbuf + (size_t)(b * 1024 + qrow) * 256 + hi * 8;
    bf8_t qf[16];
    #pragma unroll
    for (int tc = 0; tc < 16; tc++) qf[tc] = *(const bf8_t*)(qptr + tc * 16);

    float l_r = 0.f;
    f16x_t o_acc[4];
    #pragma unroll
    for (int dt = 0; dt < 4; dt++) o_acc[dt] = (f16x_t)0.0f;

    // K staging only: per STAGE 32 KB over 256 threads = 8 GLOAD16/thread
#define STAGE(T, BUF)                                                                     \
    {                                                                                     \
        _Pragma("unroll")                                                                 \
        for (int g2 = 0; g2 < 2; g2++) {                                                  \
            _Pragma("unroll")                                                             \
            for (int it = 0; it < 4; it++) {                                              \
                int cid = it * 256 + tid;                                                 \
                int chunk = cid >> 5, kvl = cid & 31;                                     \
                const u16* gk = kt + (((size_t)b * 32 + chunk) * 1024                     \
                                      + g2 * 512 + (T) * 32 + kvl) * 8;                   \
                GLOAD16(gk, &K_lds[g2][BUF][cid * 8]);                                    \
            }                                                                             \
        }                                                                                 \
    }

    // prologue: 2-deep prefetch; drain stage(0) (leave stage(1)'s 8 in flight)
    STAGE(0, 0);
    STAGE(1, 1);
    asm volatile("s_waitcnt vmcnt(8)" ::: "memory");
    __builtin_amdgcn_s_barrier();

    for (int t = 0; t < 16; ++t) {
        const int buf = t & 1;

        // ---- batched K fragment reads, forced live ----
        const u16* kb = &K_lds[g][buf][0];
        bf8_t kf[16];
        #pragma unroll
        for (int tc = 0; tc < 16; tc++)
            kf[tc] = *(const bf8_t*)(kb + ((tc * 2 + hi) * 32 + lq) * 8);
        #pragma unroll
        for (int tc = 0; tc < 16; tc++) KEEPALIVE(kf[tc]);

        // ---- V fragment loads direct from L2 (coalesced via vt3 layout);
        //      issued before QK so latency hides under QK + softmax ----
        bf8_t vf[8];
        #pragma unroll
        for (int dt = 0; dt < 4; dt++) {
            int vrow = dw * 128 + dt * 32 + lq;
            vf[2 * dt]     = *(const bf8_t*)(vt3 + (((size_t)b * 128 + g * 64 + t * 4 + hi) * 256 + vrow) * 8);
            vf[2 * dt + 1] = *(const bf8_t*)(vt3 + (((size_t)b * 128 + g * 64 + t * 4 + 2 + hi) * 256 + vrow) * 8);
        }
        #pragma unroll
        for (int j = 0; j < 8; j++) KEEPALIVE(vf[j]);

        // ---- QK^T: S^T[32kv][32q] ----
        f16x_t s0 = (f16x_t)0.0f, s1 = (f16x_t)0.0f;
        __builtin_amdgcn_s_setprio(1);
        #pragma unroll
        for (int tc = 0; tc < 8; tc++) {
            s0 = __builtin_amdgcn_mfma_f32_32x32x16_bf16(kf[2 * tc],     qf[2 * tc],     s0, 0, 0, 0);
            s1 = __builtin_amdgcn_mfma_f32_32x32x16_bf16(kf[2 * tc + 1], qf[2 * tc + 1], s1, 0, 0, 0);
        }
        __builtin_amdgcn_s_setprio(0);

        f16x_t s = s0 + s1;

        // ---- softmax (no max tracking; Q pre-scaled by log2e/16): P = 2^S ----
        float sum = 0.f;
        #pragma unroll
        for (int r = 0; r < 16; r++) { s[r] = exp2f(s[r]); sum += s[r]; }
        l_r += sum;

        // ---- pack P^T B-fragments via permlane32_swap ----
        unsigned pw[8];
        #pragma unroll
        for (int j = 0; j < 8; j++) pw[j] = cvt_pk_bf16(s[2 * j], s[2 * j + 1]);
        bf8_t f0v, f1v;
        pack_frags(pw, f0v, f1v);

        // ---- single sync point: our LDS reads done (lgkm) AND stage(t+1) +
        //      this iter's V loads landed (vmcnt) ----
        asm volatile("s_waitcnt vmcnt(0) lgkmcnt(0)" ::: "memory");
        __builtin_amdgcn_s_barrier();
        if (t < 14) STAGE(t + 2, buf);

        // ---- PV: O^T[d][q] += V^T[d][kv] P^T[kv][q] (all operands in regs) ----
        __builtin_amdgcn_s_setprio(1);
        #pragma unroll
        for (int dt = 0; dt < 4; dt++) {
            o_acc[dt] = __builtin_amdgcn_mfma_f32_32x32x16_bf16(vf[2 * dt],     f0v, o_acc[dt], 0, 0, 0);
            o_acc[dt] = __builtin_amdgcn_mfma_f32_32x32x16_bf16(vf[2 * dt + 1], f1v, o_acc[dt], 0, 0, 0);
        }
        __builtin_amdgcn_s_setprio(0);
    }

    __syncthreads();   // all waves out of the loop before LDS reuse

    // ---- stage 1: g==1 waves park raw partials (32 KB) + l in K_lds ----
    float l_tot = l_r + __shfl_xor(l_r, 32);
    float* obuf = (float*)&K_lds[0][0][0];               // bytes 0..32767
    float* rb = obuf + dw * 4096;                        // [128 d][32 q] f32
    if (g == 1) {
        #pragma unroll
        for (int dt = 0; dt < 4; dt++)
            #pragma unroll
            for (int r = 0; r < 16; r++) {
                int drow = dt * 32 + (r & 3) + 8 * (r >> 2) + 4 * hi;
                rb[drow * 32 + lq] = o_acc[dt][r];
            }
        if (dw == 0 && hi == 0) lstat[lq] = l_tot;
    }
    __syncthreads();

    // ---- stage 2: g==0 waves merge + write O bf16 (disjoint 16 KB region) ----
    u16* O16 = (u16*)((char*)&K_lds[0][0][0] + 32768);   // [d>>3][32 tok][8]
    if (g == 0) {
        float inv = 1.0f / (l_tot + lstat[lq]);
        #pragma unroll
        for (int dt = 0; dt < 4; dt++)
            #pragma unroll
            for (int r = 0; r < 16; r++) {
                int drow = dt * 32 + (r & 3) + 8 * (r >> 2) + 4 * hi;
                int d = dw * 128 + drow;
                float val = (o_acc[dt][r] + rb[drow * 32 + lq]) * inv;
                O16[((d >> 3) * 32 + lq) * 8 + (d & 7)] = f2bf(val);
            }
    }
    __syncthreads();

    // ---- proj GEMM: out = wp x O^T + bp + x; wave owns 64 out-channels ----
    #pragma unroll
    for (int cset = 0; cset < 2; cset++) {
        const int cb = wv * 64 + cset * 32;
        bf8_t wpf[16];
        #pragma unroll
        for (int tc = 0; tc < 16; tc++)
            wpf[tc] = *(const bf8_t*)(wpt + (((tc * 2 + hi) * 256) + cb + lq) * 8);
        f16x_t p = (f16x_t)0.0f;
        __builtin_amdgcn_s_setprio(1);
        #pragma unroll
        for (int tc = 0; tc < 16; tc++) {
            bf8_t of = *(const bf8_t*)(O16 + ((tc * 2 + hi) * 32 + lq) * 8);
            p = __builtin_amdgcn_mfma_f32_32x32x16_bf16(wpf[tc], of, p, 0, 0, 0);
        }
        __builtin_amdgcn_s_setprio(0);
        #pragma unroll
        for (int r = 0; r < 16; r++) {
            int crow = cb + (r & 3) + 8 * (r >> 2) + 4 * hi;
            size_t base = ((size_t)b * 256 + crow) * 1024 + qt * 32;
            out[base + lq] = p[r] + bp[crow] + x[base + lq];
        }
    }
#undef STAGE
}

extern "C" void kernel_launch(void* const* d_in, const int* in_sizes, int n_in,
                              void* d_out, int out_size, void* d_ws, size_t ws_size,
                              hipStream_t stream) {
    (void)in_sizes; (void)n_in; (void)out_size; (void)ws_size;
    const float* x   = (const float*)d_in[0];
    const float* lnw = (const float*)d_in[1];
    const float* lnb = (const float*)d_in[2];
    const float* wq  = (const float*)d_in[3];
    const float* bq  = (const float*)d_in[4];
    const float* wk  = (const float*)d_in[5];
    const float* bk  = (const float*)d_in[6];
    const float* wv  = (const float*)d_in[7];
    const float* bv  = (const float*)d_in[8];
    const float* wp  = (const float*)d_in[9];
    const float* bp  = (const float*)d_in[10];
    float* out = (float*)d_out;

    char* ws = (char*)d_ws;
    u16*   wcatT = (u16*)(ws);              // [32][768][8] bf16 (384KB)
    u16*   wpt   = (u16*)(ws + 0x60000);    // [32][256][8] bf16 (128KB)
    float* biasc = (float*)(ws + 0x80000);  // 768 f32
    u16*   qbuf  = (u16*)(ws + 0x90000);    // 16384*256 bf16   (8MB)
    u16*   kt    = (u16*)(ws + 0x890000);   // [16][32][1024][8] bf16 (8MB)
    u16*   vt3   = (u16*)(ws + 0x1090000);  // [16][128][256][8] bf16 (8MB)

    prep_kernel<<<1028, 256, 0, stream>>>(wq, wk, wv, wp, bq, bk, bv, wcatT, wpt, biasc);
    // fused LayerNorm + QKV projection (vectorized pack/stores)
    lnqkv_kernel<<<512, 256, 0, stream>>>(x, lnw, lnb, wcatT, biasc, qbuf, kt, vt3);
    // fused attention + proj: V direct from L2, 2 independent 4-wave blocks/CU
    flash_kernel<<<512, 256, 0, stream>>>(qbuf, kt, vt3, wpt, bp, x, out);
}

// Round 20
// 66.707 us; speedup vs baseline: 1.5491x; 1.5491x over previous
//
#include <hip/hip_runtime.h>
#include <hip/hip_bf16.h>
#include <stdint.h>
#include <math.h>

typedef __attribute__((ext_vector_type(8))) short bf8_t;    // 8 bf16 in 4 VGPRs
typedef __attribute__((ext_vector_type(4))) float f4_t;
typedef __attribute__((ext_vector_type(16))) float f16x_t;  // 32x32 mfma acc
typedef __attribute__((ext_vector_type(2))) unsigned u32x2;
typedef unsigned short u16;

#define GLOAD16(g, l) __builtin_amdgcn_global_load_lds(                                  \
    (const __attribute__((address_space(1))) void*)(g),                                  \
    (__attribute__((address_space(3))) void*)(l), 16, 0, 0)

#define KEEPALIVE(v) asm volatile("" : "+v"(v))

// Q pre-scale: (1/16) * log2(e)  -> softmax uses exp2 (bare v_exp_f32)
#define QSCALE 0.090168444f

__device__ __forceinline__ u16 f2bf(float f) {
    union { float f; unsigned u; } c; c.f = f;
    unsigned u = c.u;
    return (u16)((u + 0x7fffu + ((u >> 16) & 1u)) >> 16);   // RNE, inputs finite
}

__device__ __forceinline__ unsigned cvt_pk_bf16(float lo, float hi_) {
    unsigned r;
    asm("v_cvt_pk_bf16_f32 %0, %1, %2" : "=v"(r) : "v"(lo), "v"(hi_));
    return r;                                                // lo -> bits[15:0]
}

// v_permlane32_swap_b32: A[0:31] <-> B[32:63].
__device__ __forceinline__ void plswap(unsigned& a, unsigned& b) {
    u32x2 r = __builtin_amdgcn_permlane32_swap(a, b, false, false);
    a = r[0]; b = r[1];
}

// pack P fragments from 8 cvt_pk words: f0 = kv chunk0, f1 = kv chunk1
__device__ __forceinline__ void pack_frags(const unsigned* pw, bf8_t& f0v, bf8_t& f1v) {
    unsigned w0 = pw[0], w1 = pw[1], w2 = pw[2], w3 = pw[3];
    unsigned u0 = pw[4], u1 = pw[5], u2 = pw[6], u3 = pw[7];
    plswap(w2, w0);
    plswap(w3, w1);
    plswap(u2, u0);
    plswap(u3, u1);
    union { unsigned w[4]; bf8_t v; } f0, f1;
    f0.w[0] = w0; f0.w[1] = w1; f0.w[2] = w2; f0.w[3] = w3;
    f1.w[0] = u0; f1.w[1] = u1; f1.w[2] = u2; f1.w[3] = u3;
    f0v = f0.v; f1v = f1.v;
}

// ---------------- weights -> bf16 ----------------
// wcatT: [c>>3][768 out][8]  (QKV weights, chunked: fragment reads coalesce)
// wpt:   [d>>3][256 out][8]  (proj weights)
__global__ void prep_kernel(const float* __restrict__ wq, const float* __restrict__ wk,
                            const float* __restrict__ wv, const float* __restrict__ wp,
                            const float* __restrict__ bq, const float* __restrict__ bk,
                            const float* __restrict__ bv,
                            u16* __restrict__ wcatT, u16* __restrict__ wpt,
                            float* __restrict__ biasc) {
    int idx = blockIdx.x * 256 + threadIdx.x;
    if (idx < 196608) {                 // QKV weights
        int o = idx >> 8, c = idx & 255;
        float v = (o < 256) ? wq[o * 256 + c]
                : (o < 512) ? wk[(o - 256) * 256 + c]
                            : wv[(o - 512) * 256 + c];
        wcatT[(((c >> 3) * 768) + o) * 8 + (c & 7)] = f2bf(v);
    } else if (idx < 262144) {          // wp[o][d] -> wpt[(d>>3)][o][8]
        int i = idx - 196608;
        int o = i >> 8, d = i & 255;
        wpt[(((d >> 3) * 256) + o) * 8 + (d & 7)] = f2bf(wp[i]);
    } else if (idx < 262912) {          // bias concat [768]
        int i = idx - 262144;
        biasc[i] = (i < 256) ? bq[i] : (i < 512) ? bk[i - 256] : bv[i - 512];
    }
}

// ---------------- fused LayerNorm + QKV GEMM (v3: vectorized stores) ----------------
// grid 512 = (b, n-tile of 32); 256 threads = 4 waves; 18 KB LDS.
__global__ __launch_bounds__(256) void lnqkv_kernel(
    const float* __restrict__ x, const float* __restrict__ lw,
    const float* __restrict__ lb,
    const u16* __restrict__ wcatT, const float* __restrict__ biasc,
    u16* __restrict__ qbuf, u16* __restrict__ ktp, u16* __restrict__ vtp) {
    __shared__ u16 hn_lds[32 * 32 * 8];      // [chunk][tok][8], 16 KB
    __shared__ float2 red[8][32];            // 2 KB

    const int tid = threadIdx.x;
    const int bid = blockIdx.x;
    const int b = bid >> 5, n0 = (bid & 31) * 32;
    const int tok = tid & 31, cpart = tid >> 5;      // 8 parts x 32 channels

    // ---- LN: each thread owns 32 channels of one token ----
    const float* xb = x + (size_t)b * 262144 + n0 + tok;
    float v[32];
    float s = 0.f, s2 = 0.f;
    #pragma unroll
    for (int i = 0; i < 32; i++) {
        v[i] = xb[(size_t)(cpart * 32 + i) * 1024];
        s += v[i]; s2 += v[i] * v[i];
    }
    red[cpart][tok] = make_float2(s, s2);
    __syncthreads();
    s = 0.f; s2 = 0.f;
    #pragma unroll
    for (int gi = 0; gi < 8; gi++) { float2 p = red[gi][tok]; s += p.x; s2 += p.y; }
    float mean = s * 0.00390625f;
    float rstd = rsqrtf(s2 * 0.00390625f - mean * mean + 1e-6f);
    #pragma unroll
    for (int j = 0; j < 4; j++) {            // 4 chunks of 8 channels
        bf8_t pk;
        #pragma unroll
        for (int e = 0; e < 8; e++) {
            int c = cpart * 32 + j * 8 + e;
            pk[e] = (short)f2bf((v[j * 8 + e] - mean) * rstd * lw[c] + lb[c]);
        }
        *(bf8_t*)&hn_lds[((cpart * 4 + j) * 32 + tok) * 8] = pk;
    }
    __syncthreads();                         // hn complete; GEMM is barrier-free

    // ---- GEMM: out[32 tok][768], 24 col-tiles of 32, 6 per wave ----
    const int lane = tid & 63, wv_ = tid >> 6;
    const int hi = lane >> 5, lq = lane & 31;
    const int n = n0 + lq;

    // hn fragments: shared across all tiles of this wave
    bf8_t hnf[16];
    #pragma unroll
    for (int tc = 0; tc < 16; tc++)
        hnf[tc] = *(const bf8_t*)&hn_lds[((tc * 2 + hi) * 32 + lq) * 8];
    #pragma unroll
    for (int tc = 0; tc < 16; tc++) KEEPALIVE(hnf[tc]);

    #pragma unroll
    for (int grp = 0; grp < 3; grp++) {
        #pragma unroll
        for (int sub = 0; sub < 2; sub++) {
            const int cb = grp * 256 + (wv_ * 2 + sub) * 32;
            bf8_t wf[16];
            #pragma unroll
            for (int tc = 0; tc < 16; tc++)
                wf[tc] = *(const bf8_t*)(wcatT + (((size_t)(tc * 2 + hi) * 768) + cb + lq) * 8);
            f16x_t acc = (f16x_t)0.0f;
            if (grp < 2) {
                // swapped: lane = token, regs = channels
                #pragma unroll
                for (int tc = 0; tc < 16; tc++)
                    acc = __builtin_amdgcn_mfma_f32_32x32x16_bf16(wf[tc], hnf[tc], acc, 0, 0, 0);
                #pragma unroll
                for (int r = 0; r < 16; r++) {
                    float bv = biasc[cb + (r & 3) + 8 * (r >> 2) + 4 * hi];
                    acc[r] += bv;
                    if (grp == 0) acc[r] *= QSCALE;
                }
            } else {
                // normal: lane = channel d, regs = tokens
                #pragma unroll
                for (int tc = 0; tc < 16; tc++)
                    acc = __builtin_amdgcn_mfma_f32_32x32x16_bf16(hnf[tc], wf[tc], acc, 0, 0, 0);
                float bv = biasc[cb + lq];
                #pragma unroll
                for (int r = 0; r < 16; r++) acc[r] += bv;
            }

            unsigned pw[8];
            #pragma unroll
            for (int j = 0; j < 8; j++) pw[j] = cvt_pk_bf16(acc[2 * j], acc[2 * j + 1]);
            bf8_t f0v, f1v;
            pack_frags(pw, f0v, f1v);

            if (grp == 0) {                  // Q row-major [tok][256]
                u16* qb = &qbuf[((size_t)b * 1024 + n) * 256 + cb];
                *(bf8_t*)(qb + hi * 8) = f0v;
                *(bf8_t*)(qb + 16 + hi * 8) = f1v;
            } else if (grp == 1) {           // K -> kt[b][c>>3][n][8]
                int c0 = cb - 256 + hi * 8;
                *(bf8_t*)&ktp[(((size_t)b * 32 + (c0 >> 3)) * 1024 + n) * 8] = f0v;
                int c1 = c0 + 16;
                *(bf8_t*)&ktp[(((size_t)b * 32 + (c1 >> 3)) * 1024 + n) * 8] = f1v;
            } else {                         // V -> vt3[b][n>>3][d][8]
                int d = cb - 512 + lq;
                int t0 = n0 + hi * 8;
                *(bf8_t*)&vtp[(((size_t)b * 128 + (t0 >> 3)) * 256 + d) * 8] = f0v;
                int t1 = t0 + 16;
                *(bf8_t*)&vtp[(((size_t)b * 128 + (t1 >> 3)) * 256 + d) * 8] = f1v;
            }
        }
    }
}

// ---------------- flash attention + fused proj ----------------
// grid 256 = (b, qb) XCD-swizzled; 512 threads = 8 waves = (qw 2) x (dw 2) x (g 2).
// Counted-vmcnt 2-deep pipeline with a SINGLE barrier per iteration:
// wait {lgkmcnt(0), vmcnt(0)=stage(t+1) only} -> barrier -> STAGE(t+2) -> PV.
__global__ __launch_bounds__(512)
__attribute__((amdgpu_waves_per_eu(2, 2)))
void flash_kernel(const u16* __restrict__ qbuf,
                  const u16* __restrict__ kt,
                  const u16* __restrict__ vt3,
                  const u16* __restrict__ wpt,
                  const float* __restrict__ bp,
                  const float* __restrict__ x,
                  float* __restrict__ out) {
    __shared__ u16 K_lds[2][2][32 * 32 * 8];   // [g][buf][chunk][kv] 16B units, 64 KB
    __shared__ u16 V_lds[2][2][4 * 256 * 8];   // [g][buf][kc][d]    16B units, 64 KB
    __shared__ float lstat[2][32];

    const int flat = blockIdx.x;
    const int xcd = flat & 7, idx = flat >> 3;
    const int b = (xcd << 1) | (idx & 1);     // 2 batches per XCD -> KV fits L2
    const int qb = idx >> 1;
    const int tid = threadIdx.x;
    const int wv = tid >> 6, lane = tid & 63;
    const int hi = lane >> 5, lq = lane & 31;
    const int qw = wv & 1, dw = (wv >> 1) & 1, g = wv >> 2;

    // Q B-fragments: col=q=lq, chunk tc covers c = tc*16 + hi*8 + e
    const int qrow = qb * 64 + qw * 32 + lq;
    const u16* qptr = qbuf + (size_t)(b * 1024 + qrow) * 256 + hi * 8;
    bf8_t qf[16];
    #pragma unroll
    for (int tc = 0; tc < 16; tc++) qf[tc] = *(const bf8_t*)(qptr + tc * 16);

    float l_r = 0.f;
    f16x_t o_acc[4];
    #pragma unroll
    for (int dt = 0; dt < 4; dt++) o_acc[dt] = (f16x_t)0.0f;

#define STAGE(T, BUF)                                                                     \
    {                                                                                     \
        _Pragma("unroll")                                                                 \
        for (int g2 = 0; g2 < 2; g2++) {                                                  \
            _Pragma("unroll")                                                             \
            for (int it = 0; it < 2; it++) {                                              \
                int cid = it * 512 + tid;                                                 \
                int chunk = cid >> 5, kvl = cid & 31;                                     \
                const u16* gk = kt + (((size_t)b * 32 + chunk) * 1024                     \
                                      + g2 * 512 + (T) * 32 + kvl) * 8;                   \
                GLOAD16(gk, &K_lds[g2][BUF][cid * 8]);                                    \
            }                                                                             \
            _Pragma("unroll")                                                             \
            for (int it = 0; it < 2; it++) {                                              \
                int cid = it * 512 + tid;                                                 \
                int kc = cid >> 8, d = cid & 255;                                         \
                const u16* gv = vt3 + (((size_t)b * 128 + g2 * 64 + (T) * 4 + kc) * 256   \
                                       + d) * 8;                                          \
                GLOAD16(gv, &V_lds[g2][BUF][cid * 8]);                                    \
            }                                                                             \
        }                                                                                 \
    }

    // prologue: 2-deep prefetch; drain stage(0) (leave stage(1) in flight)
    STAGE(0, 0);
    STAGE(1, 1);
    asm volatile("s_waitcnt vmcnt(8)" ::: "memory");
    __builtin_amdgcn_s_barrier();

    for (int t = 0; t < 16; ++t) {
        const int buf = t & 1;

        // ---- batched K fragment reads, forced live ----
        const u16* kb = &K_lds[g][buf][0];
        bf8_t kf[16];
        #pragma unroll
        for (int tc = 0; tc < 16; tc++)
            kf[tc] = *(const bf8_t*)(kb + ((tc * 2 + hi) * 32 + lq) * 8);
        #pragma unroll
        for (int tc = 0; tc < 16; tc++) KEEPALIVE(kf[tc]);

        // ---- QK^T: S^T[32kv][32q] ----
        f16x_t s0 = (f16x_t)0.0f, s1 = (f16x_t)0.0f;
        __builtin_amdgcn_s_setprio(1);
        #pragma unroll
        for (int tc = 0; tc < 8; tc++) {
            s0 = __builtin_amdgcn_mfma_f32_32x32x16_bf16(kf[2 * tc],     qf[2 * tc],     s0, 0, 0, 0);
            s1 = __builtin_amdgcn_mfma_f32_32x32x16_bf16(kf[2 * tc + 1], qf[2 * tc + 1], s1, 0, 0, 0);
        }
        __builtin_amdgcn_s_setprio(0);

        // ---- batched V fragment reads, forced live ----
        const u16* vb = &V_lds[g][buf][0];
        bf8_t vf[8];
        #pragma unroll
        for (int dt = 0; dt < 4; dt++) {
            int vrow = dw * 128 + dt * 32 + lq;
            vf[2 * dt]     = *(const bf8_t*)(vb + (hi * 256 + vrow) * 8);
            vf[2 * dt + 1] = *(const bf8_t*)(vb + ((2 + hi) * 256 + vrow) * 8);
        }
        #pragma unroll
        for (int j = 0; j < 8; j++) KEEPALIVE(vf[j]);

        f16x_t s = s0 + s1;

        // ---- softmax (no max tracking; Q pre-scaled by log2e/16): P = 2^S ----
        float sum = 0.f;
        #pragma unroll
        for (int r = 0; r < 16; r++) { s[r] = exp2f(s[r]); sum += s[r]; }
        l_r += sum;

        // ---- pack P^T B-fragments via permlane32_swap ----
        unsigned pw[8];
        #pragma unroll
        for (int j = 0; j < 8; j++) pw[j] = cvt_pk_bf16(s[2 * j], s[2 * j + 1]);
        bf8_t f0v, f1v;
        pack_frags(pw, f0v, f1v);

        // ---- single sync point: our LDS reads done (lgkm) AND stage(t+1)
        //      landed (vmcnt: only stage(t+1) is outstanding here) ----
        asm volatile("s_waitcnt vmcnt(0) lgkmcnt(0)" ::: "memory");
        __builtin_amdgcn_s_barrier();
        if (t < 14) STAGE(t + 2, buf);

        // ---- PV: O^T[d][q] += V^T[d][kv] P^T[kv][q] (all operands in regs) ----
        __builtin_amdgcn_s_setprio(1);
        #pragma unroll
        for (int dt = 0; dt < 4; dt++) {
            o_acc[dt] = __builtin_amdgcn_mfma_f32_32x32x16_bf16(vf[2 * dt],     f0v, o_acc[dt], 0, 0, 0);
            o_acc[dt] = __builtin_amdgcn_mfma_f32_32x32x16_bf16(vf[2 * dt + 1], f1v, o_acc[dt], 0, 0, 0);
        }
        __builtin_amdgcn_s_setprio(0);
    }

    __syncthreads();   // all waves out of the loop before LDS reuse

    // ---- stage 1: g==1 waves park raw partials + l in K_lds ----
    float l_tot = l_r + __shfl_xor(l_r, 32);
    float* obuf = (float*)&K_lds[0][0][0];               // 4 x 4096 f32 = 64 KB
    float* rb = obuf + (qw * 2 + dw) * 4096;
    if (g == 1) {
        #pragma unroll
        for (int dt = 0; dt < 4; dt++)
            #pragma unroll
            for (int r = 0; r < 16; r++) {
                int drow = dt * 32 + (r & 3) + 8 * (r >> 2) + 4 * hi;
                rb[drow * 32 + lq] = o_acc[dt][r];
            }
        if (dw == 0 && hi == 0) lstat[qw][lq] = l_tot;
    }
    __syncthreads();

    // prefetch proj weight fragments (L2-hot; latency hides under merge)
    bf8_t wpf[16];
    #pragma unroll
    for (int tc = 0; tc < 16; tc++)
        wpf[tc] = *(const bf8_t*)(wpt + (((tc * 2 + hi) * 256) + wv * 32 + lq) * 8);

    // ---- stage 2: g==0 waves merge, write O tile bf16 to LDS [d>>3][64n][8] ----
    u16* O16 = (u16*)&V_lds[0][0][0];                    // 32 KB
    if (g == 0) {
        float inv = 1.0f / (l_tot + lstat[qw][lq]);
        #pragma unroll
        for (int dt = 0; dt < 4; dt++)
            #pragma unroll
            for (int r = 0; r < 16; r++) {
                int drow = dt * 32 + (r & 3) + 8 * (r >> 2) + 4 * hi;
                int d = dw * 128 + drow;
                float val = (o_acc[dt][r] + rb[drow * 32 + lq]) * inv;
                O16[((d >> 3) * 64 + qw * 32 + lq) * 8 + (d & 7)] = f2bf(val);
            }
    }
    __syncthreads();

    // ---- stage 3: all 8 waves: proj GEMM out = wp x O^T + bp + x ----
    f16x_t p0 = (f16x_t)0.0f, p1 = (f16x_t)0.0f;
    __builtin_amdgcn_s_setprio(1);
    #pragma unroll
    for (int tc = 0; tc < 16; tc++) {
        bf8_t of0 = *(const bf8_t*)(O16 + ((tc * 2 + hi) * 64 + lq) * 8);
        bf8_t of1 = *(const bf8_t*)(O16 + ((tc * 2 + hi) * 64 + 32 + lq) * 8);
        p0 = __builtin_amdgcn_mfma_f32_32x32x16_bf16(wpf[tc], of0, p0, 0, 0, 0);
        p1 = __builtin_amdgcn_mfma_f32_32x32x16_bf16(wpf[tc], of1, p1, 0, 0, 0);
    }
    __builtin_amdgcn_s_setprio(0);
    #pragma unroll
    for (int r = 0; r < 16; r++) {
        int crow = wv * 32 + (r & 3) + 8 * (r >> 2) + 4 * hi;
        size_t base = ((size_t)b * 256 + crow) * 1024 + qb * 64;
        float bpv = bp[crow];
        out[base + lq]      = p0[r] + bpv + x[base + lq];
        out[base + 32 + lq] = p1[r] + bpv + x[base + 32 + lq];
    }
#undef STAGE
}

extern "C" void kernel_launch(void* const* d_in, const int* in_sizes, int n_in,
                              void* d_out, int out_size, void* d_ws, size_t ws_size,
                              hipStream_t stream) {
    (void)in_sizes; (void)n_in; (void)out_size; (void)ws_size;
    const float* x   = (const float*)d_in[0];
    const float* lnw = (const float*)d_in[1];
    const float* lnb = (const float*)d_in[2];
    const float* wq  = (const float*)d_in[3];
    const float* bq  = (const float*)d_in[4];
    const float* wk  = (const float*)d_in[5];
    const float* bk  = (const float*)d_in[6];
    const float* wv  = (const float*)d_in[7];
    const float* bv  = (const float*)d_in[8];
    const float* wp  = (const float*)d_in[9];
    const float* bp  = (const float*)d_in[10];
    float* out = (float*)d_out;

    char* ws = (char*)d_ws;
    u16*   wcatT = (u16*)(ws);              // [32][768][8] bf16 (384KB)
    u16*   wpt   = (u16*)(ws + 0x60000);    // [32][256][8] bf16 (128KB)
    float* biasc = (float*)(ws + 0x80000);  // 768 f32
    u16*   qbuf  = (u16*)(ws + 0x90000);    // 16384*256 bf16   (8MB)
    u16*   kt    = (u16*)(ws + 0x890000);   // [16][32][1024][8] bf16 (8MB)
    u16*   vt3   = (u16*)(ws + 0x1090000);  // [16][128][256][8] bf16 (8MB)

    prep_kernel<<<1028, 256, 0, stream>>>(wq, wk, wv, wp, bq, bk, bv, wcatT, wpt, biasc);
    // fused LayerNorm + QKV projection (vectorized pack/stores)
    lnqkv_kernel<<<512, 256, 0, stream>>>(x, lnw, lnb, wcatT, biasc, qbuf, kt, vt3);
    // fused attention + proj (+bias +residual): single-barrier pipeline
    flash_kernel<<<256, 512, 0, stream>>>(qbuf, kt, vt3, wpt, bp, x, out);
}